// Round 1
// baseline (558.811 us; speedup 1.0000x reference)
//
#include <hip/hip_runtime.h>
#include <math.h>

#define N_NODES 50000
#define E_EDGES 800000
#define NEG_SLOPE 0.2f
#define BN_EPS 1e-5f

// ---------------- init ----------------
__global__ void k_zero(int* __restrict__ counts, float* __restrict__ bn_sum,
                       float* __restrict__ bn_sumsq) {
  int i = blockIdx.x * 256 + threadIdx.x;
  if (i < N_NODES + 1) counts[i] = 0;
  if (i < 128) { bn_sum[i] = 0.f; bn_sumsq[i] = 0.f; }
}

// ---------------- CSR build ----------------
__global__ void k_hist(const int* __restrict__ dst, int* __restrict__ counts) {
  int e = blockIdx.x * 256 + threadIdx.x;
  if (e < E_EDGES) atomicAdd(&counts[dst[e]], 1);
}

__global__ void k_scan(const int* __restrict__ counts, int* __restrict__ row_ptr,
                       int* __restrict__ cursor) {
  __shared__ int s[1024];
  const int n = N_NODES;
  int t = threadIdx.x;
  int chunk = (n + 1023) >> 10;
  int begin = t * chunk;
  int end = begin + chunk; if (end > n) end = n;
  int sum = 0;
  for (int i = begin; i < end; i++) sum += counts[i];
  s[t] = sum;
  __syncthreads();
  for (int off = 1; off < 1024; off <<= 1) {
    int v = (t >= off) ? s[t - off] : 0;
    __syncthreads();
    s[t] += v;
    __syncthreads();
  }
  int run = (t == 0) ? 0 : s[t - 1];
  for (int i = begin; i < end; i++) {
    row_ptr[i] = run;
    cursor[i] = run;
    run += counts[i];
  }
  if (t == 1023) row_ptr[n] = run;
}

__global__ void k_scatter(const int* __restrict__ src, const int* __restrict__ dst,
                          int* __restrict__ cursor, int* __restrict__ csr_src) {
  int e = blockIdx.x * 256 + threadIdx.x;
  if (e < E_EDGES) {
    int d = dst[e];
    int pos = atomicAdd(&cursor[d], 1);
    csr_src[pos] = src[e];
  }
}

// ---------------- layer 0 GEMM: h0 = x @ W0, + fused attention dots ----------------
// block 256 threads, tile 64 rows x 128 cols; thread: tr=t>>5 (8 rows each), tc=t&31 (4 cols each)
__global__ __launch_bounds__(256) void k_gemm0(
    const float* __restrict__ x, const float* __restrict__ W,
    const float* __restrict__ att_s, const float* __restrict__ att_d,
    float* __restrict__ h, float* __restrict__ a_src, float* __restrict__ a_dst) {
  __shared__ float xs[64 * 132];
  int t = threadIdx.x;
  int rowBase = blockIdx.x * 64;
  // stage x tile (zero-pad OOB rows)
#pragma unroll
  for (int j = 0; j < 8; j++) {
    int id = t + 256 * j;
    int row = id >> 5;
    int kk = (id & 31) * 4;
    float4 v = make_float4(0.f, 0.f, 0.f, 0.f);
    int gr = rowBase + row;
    if (gr < N_NODES) v = *(const float4*)&x[(size_t)gr * 128 + kk];
    *(float4*)&xs[row * 132 + kk] = v;
  }
  __syncthreads();

  int tc = t & 31, tr = t >> 5;
  int c = tc * 4, r0 = tr * 8;
  float acc[8][4];
#pragma unroll
  for (int i = 0; i < 8; i++)
#pragma unroll
    for (int j = 0; j < 4; j++) acc[i][j] = 0.f;

  for (int k4 = 0; k4 < 128; k4 += 4) {
    float4 wv[4];
#pragma unroll
    for (int kk = 0; kk < 4; kk++) wv[kk] = *(const float4*)&W[(k4 + kk) * 128 + c];
    float4 xv[8];
#pragma unroll
    for (int i = 0; i < 8; i++) xv[i] = *(const float4*)&xs[(r0 + i) * 132 + k4];
#pragma unroll
    for (int i = 0; i < 8; i++) {
      acc[i][0] += xv[i].x * wv[0].x + xv[i].y * wv[1].x + xv[i].z * wv[2].x + xv[i].w * wv[3].x;
      acc[i][1] += xv[i].x * wv[0].y + xv[i].y * wv[1].y + xv[i].z * wv[2].y + xv[i].w * wv[3].y;
      acc[i][2] += xv[i].x * wv[0].z + xv[i].y * wv[1].z + xv[i].z * wv[2].z + xv[i].w * wv[3].z;
      acc[i][3] += xv[i].x * wv[0].w + xv[i].y * wv[1].w + xv[i].z * wv[2].w + xv[i].w * wv[3].w;
    }
  }

  // epilogue: write h + fused a_src/a_dst
  float as4[4], ad4[4];
#pragma unroll
  for (int j = 0; j < 4; j++) { as4[j] = att_s[c + j]; ad4[j] = att_d[c + j]; }
  int head = tc >> 4;
#pragma unroll
  for (int i = 0; i < 8; i++) {
    int gr = rowBase + r0 + i;
    float ps = acc[i][0] * as4[0] + acc[i][1] * as4[1] + acc[i][2] * as4[2] + acc[i][3] * as4[3];
    float pd = acc[i][0] * ad4[0] + acc[i][1] * ad4[1] + acc[i][2] * ad4[2] + acc[i][3] * ad4[3];
#pragma unroll
    for (int msk = 1; msk <= 8; msk <<= 1) {
      ps += __shfl_xor(ps, msk);
      pd += __shfl_xor(pd, msk);
    }
    if (gr < N_NODES) {
      float4 hv = make_float4(acc[i][0], acc[i][1], acc[i][2], acc[i][3]);
      *(float4*)&h[(size_t)gr * 128 + c] = hv;
      if ((t & 15) == 0) {
        a_src[gr * 2 + head] = ps;
        a_dst[gr * 2 + head] = pd;
      }
    }
  }
}

// ---------------- layer 0 aggregation: one wave per node, online softmax ----------------
__global__ __launch_bounds__(256) void k_agg0(
    const int* __restrict__ row_ptr, const int* __restrict__ csr_src,
    const float* __restrict__ h, const float* __restrict__ a_src,
    const float* __restrict__ a_dst, const float* __restrict__ bias,
    float* __restrict__ out) {
  int node = (blockIdx.x * blockDim.x + threadIdx.x) >> 6;
  if (node >= N_NODES) return;
  int l = threadIdx.x & 63;
  int head = l >> 5;
  int c = l * 2;
  float ad = a_dst[node * 2 + head];
  float e = a_src[node * 2 + head] + ad;
  e = e > 0.f ? e : NEG_SLOPE * e;  // self-loop edge
  float m = e, d = 1.f;
  float2 hv = *(const float2*)&h[(size_t)node * 128 + c];
  float acc0 = hv.x, acc1 = hv.y;
  int beg = row_ptr[node], end = row_ptr[node + 1];
  for (int i = beg; i < end; i++) {
    int s = csr_src[i];
    float ee = a_src[s * 2 + head] + ad;
    ee = ee > 0.f ? ee : NEG_SLOPE * ee;
    float2 hh = *(const float2*)&h[(size_t)s * 128 + c];
    float nm = fmaxf(m, ee);
    float sc = __expf(m - nm);
    float w = __expf(ee - nm);
    d = d * sc + w;
    acc0 = acc0 * sc + w * hh.x;
    acc1 = acc1 * sc + w * hh.y;
    m = nm;
  }
  float inv = 1.f / d;
  float2 o;
  o.x = acc0 * inv + bias[c];
  o.y = acc1 * inv + bias[c + 1];
  *(float2*)&out[(size_t)node * 128 + c] = o;
}

// ---------------- BatchNorm stats ----------------
__global__ __launch_bounds__(256) void k_bnstats(const float* __restrict__ x,
                                                 float* __restrict__ bn_sum,
                                                 float* __restrict__ bn_sumsq) {
  int f = threadIdx.x & 127;
  int half = threadIdx.x >> 7;
  float s = 0.f, s2 = 0.f;
  for (int r = blockIdx.x * 2 + half; r < N_NODES; r += gridDim.x * 2) {
    float v = x[(size_t)r * 128 + f];
    s += v;
    s2 += v * v;
  }
  __shared__ float ls[256], ls2[256];
  ls[threadIdx.x] = s;
  ls2[threadIdx.x] = s2;
  __syncthreads();
  if (half == 0) {
    atomicAdd(&bn_sum[f], s + ls[f + 128]);
    atomicAdd(&bn_sumsq[f], s2 + ls2[f + 128]);
  }
}

__global__ void k_bnfinal(const float* __restrict__ sum, const float* __restrict__ sumsq,
                          const float* __restrict__ gamma, const float* __restrict__ beta,
                          float* __restrict__ scale, float* __restrict__ shift) {
  int f = threadIdx.x;
  float mu = sum[f] / (float)N_NODES;
  float var = sumsq[f] / (float)N_NODES - mu * mu;
  float sc = gamma[f] * rsqrtf(var + BN_EPS);
  scale[f] = sc;
  shift[f] = beta[f] - mu * sc;
}

// ---------------- layer 1 GEMM (BN+ELU fused on load): h1 = elu(bn(out0)) @ W1 ----------------
// block 256 threads, tile 64 rows x 64 cols; thread: tr=t>>4 (4 rows each), tc=t&15 (4 cols each)
__global__ __launch_bounds__(256) void k_gemm1(
    const float* __restrict__ x, const float* __restrict__ W,
    const float* __restrict__ scale, const float* __restrict__ shift,
    const float* __restrict__ att_s, const float* __restrict__ att_d,
    float* __restrict__ h, float* __restrict__ a_src, float* __restrict__ a_dst) {
  __shared__ float xs[64 * 132];
  int t = threadIdx.x;
  int rowBase = blockIdx.x * 64;
#pragma unroll
  for (int j = 0; j < 8; j++) {
    int id = t + 256 * j;
    int row = id >> 5;
    int kk = (id & 31) * 4;
    float4 v = make_float4(0.f, 0.f, 0.f, 0.f);
    int gr = rowBase + row;
    if (gr < N_NODES) {
      float4 raw = *(const float4*)&x[(size_t)gr * 128 + kk];
      float4 sc = *(const float4*)&scale[kk];
      float4 sh = *(const float4*)&shift[kk];
      v.x = raw.x * sc.x + sh.x;
      v.y = raw.y * sc.y + sh.y;
      v.z = raw.z * sc.z + sh.z;
      v.w = raw.w * sc.w + sh.w;
      v.x = v.x > 0.f ? v.x : __expf(v.x) - 1.f;
      v.y = v.y > 0.f ? v.y : __expf(v.y) - 1.f;
      v.z = v.z > 0.f ? v.z : __expf(v.z) - 1.f;
      v.w = v.w > 0.f ? v.w : __expf(v.w) - 1.f;
    }
    *(float4*)&xs[row * 132 + kk] = v;
  }
  __syncthreads();

  int tc = t & 15, tr = t >> 4;
  int c = tc * 4, r0 = tr * 4;
  float acc[4][4];
#pragma unroll
  for (int i = 0; i < 4; i++)
#pragma unroll
    for (int j = 0; j < 4; j++) acc[i][j] = 0.f;

  for (int k4 = 0; k4 < 128; k4 += 4) {
    float4 wv[4];
#pragma unroll
    for (int kk = 0; kk < 4; kk++) wv[kk] = *(const float4*)&W[(k4 + kk) * 64 + c];
    float4 xv[4];
#pragma unroll
    for (int i = 0; i < 4; i++) xv[i] = *(const float4*)&xs[(r0 + i) * 132 + k4];
#pragma unroll
    for (int i = 0; i < 4; i++) {
      acc[i][0] += xv[i].x * wv[0].x + xv[i].y * wv[1].x + xv[i].z * wv[2].x + xv[i].w * wv[3].x;
      acc[i][1] += xv[i].x * wv[0].y + xv[i].y * wv[1].y + xv[i].z * wv[2].y + xv[i].w * wv[3].y;
      acc[i][2] += xv[i].x * wv[0].z + xv[i].y * wv[1].z + xv[i].z * wv[2].z + xv[i].w * wv[3].z;
      acc[i][3] += xv[i].x * wv[0].w + xv[i].y * wv[1].w + xv[i].z * wv[2].w + xv[i].w * wv[3].w;
    }
  }

  float as4[4], ad4[4];
#pragma unroll
  for (int j = 0; j < 4; j++) { as4[j] = att_s[c + j]; ad4[j] = att_d[c + j]; }
#pragma unroll
  for (int i = 0; i < 4; i++) {
    int gr = rowBase + r0 + i;
    float ps = acc[i][0] * as4[0] + acc[i][1] * as4[1] + acc[i][2] * as4[2] + acc[i][3] * as4[3];
    float pd = acc[i][0] * ad4[0] + acc[i][1] * ad4[1] + acc[i][2] * ad4[2] + acc[i][3] * ad4[3];
#pragma unroll
    for (int msk = 1; msk <= 8; msk <<= 1) {
      ps += __shfl_xor(ps, msk);
      pd += __shfl_xor(pd, msk);
    }
    if (gr < N_NODES) {
      float4 hv = make_float4(acc[i][0], acc[i][1], acc[i][2], acc[i][3]);
      *(float4*)&h[(size_t)gr * 64 + c] = hv;
      if ((t & 15) == 0) {
        a_src[gr] = ps;
        a_dst[gr] = pd;
      }
    }
  }
}

// ---------------- layer 1 aggregation ----------------
__global__ __launch_bounds__(256) void k_agg1(
    const int* __restrict__ row_ptr, const int* __restrict__ csr_src,
    const float* __restrict__ h, const float* __restrict__ a_src,
    const float* __restrict__ a_dst, const float* __restrict__ bias,
    float* __restrict__ out) {
  int node = (blockIdx.x * blockDim.x + threadIdx.x) >> 6;
  if (node >= N_NODES) return;
  int l = threadIdx.x & 63;
  float ad = a_dst[node];
  float e = a_src[node] + ad;
  e = e > 0.f ? e : NEG_SLOPE * e;  // self loop
  float m = e, d = 1.f;
  float acc = h[(size_t)node * 64 + l];
  int beg = row_ptr[node], end = row_ptr[node + 1];
  for (int i = beg; i < end; i++) {
    int s = csr_src[i];
    float ee = a_src[s] + ad;
    ee = ee > 0.f ? ee : NEG_SLOPE * ee;
    float hh = h[(size_t)s * 64 + l];
    float nm = fmaxf(m, ee);
    float sc = __expf(m - nm);
    float w = __expf(ee - nm);
    d = d * sc + w;
    acc = acc * sc + w * hh;
    m = nm;
  }
  out[(size_t)node * 64 + l] = acc / d + bias[l];
}

// ---------------- launch ----------------
extern "C" void kernel_launch(void* const* d_in, const int* in_sizes, int n_in,
                              void* d_out, int out_size, void* d_ws, size_t ws_size,
                              hipStream_t stream) {
  const float* data = (const float*)d_in[0];
  const int* ei = (const int*)d_in[1];
  const float* W0 = (const float*)d_in[2];
  const float* att_src0 = (const float*)d_in[3];
  const float* att_dst0 = (const float*)d_in[4];
  const float* bias0 = (const float*)d_in[5];
  const float* gamma0 = (const float*)d_in[6];
  const float* beta0 = (const float*)d_in[7];
  const float* W1 = (const float*)d_in[8];
  const float* att_src1 = (const float*)d_in[9];
  const float* att_dst1 = (const float*)d_in[10];
  const float* bias1 = (const float*)d_in[11];
  float* out = (float*)d_out;

  char* ws = (char*)d_ws;
  size_t off = 0;
  auto alloc = [&](size_t bytes) -> void* {
    void* p = ws + off;
    off = (off + bytes + 255) & ~(size_t)255;
    return p;
  };
  int* row_ptr = (int*)alloc((N_NODES + 1) * 4);
  int* counts = (int*)alloc((N_NODES + 1) * 4);
  int* cursor = (int*)alloc(N_NODES * 4);
  int* csr_src = (int*)alloc((size_t)E_EDGES * 4);
  float* h0 = (float*)alloc((size_t)N_NODES * 128 * 4);
  float* a_s0 = (float*)alloc((size_t)N_NODES * 2 * 4);
  float* a_d0 = (float*)alloc((size_t)N_NODES * 2 * 4);
  float* out0 = (float*)alloc((size_t)N_NODES * 128 * 4);
  float* bn_sum = (float*)alloc(128 * 4);
  float* bn_sumsq = (float*)alloc(128 * 4);
  float* bn_scale = (float*)alloc(128 * 4);
  float* bn_shift = (float*)alloc(128 * 4);
  // layer-1 buffers alias dead layer-0 buffers (h0/a_s0/a_d0 dead after k_agg0)
  float* h1 = h0;
  float* a_s1 = a_s0;
  float* a_d1 = a_d0;

  const int* srcArr = ei;
  const int* dstArr = ei + E_EDGES;

  k_zero<<<(N_NODES + 256) / 256, 256, 0, stream>>>(counts, bn_sum, bn_sumsq);
  k_hist<<<(E_EDGES + 255) / 256, 256, 0, stream>>>(dstArr, counts);
  k_scan<<<1, 1024, 0, stream>>>(counts, row_ptr, cursor);
  k_scatter<<<(E_EDGES + 255) / 256, 256, 0, stream>>>(srcArr, dstArr, cursor, csr_src);
  k_gemm0<<<(N_NODES + 63) / 64, 256, 0, stream>>>(data, W0, att_src0, att_dst0, h0, a_s0, a_d0);
  k_agg0<<<(N_NODES + 3) / 4, 256, 0, stream>>>(row_ptr, csr_src, h0, a_s0, a_d0, bias0, out0);
  k_bnstats<<<1024, 256, 0, stream>>>(out0, bn_sum, bn_sumsq);
  k_bnfinal<<<1, 128, 0, stream>>>(bn_sum, bn_sumsq, gamma0, beta0, bn_scale, bn_shift);
  k_gemm1<<<(N_NODES + 63) / 64, 256, 0, stream>>>(out0, W1, bn_scale, bn_shift, att_src1,
                                                   att_dst1, h1, a_s1, a_d1);
  k_agg1<<<(N_NODES + 3) / 4, 256, 0, stream>>>(row_ptr, csr_src, h1, a_s1, a_d1, bias1, out);
}

// Round 3
// 456.152 us; speedup vs baseline: 1.2251x; 1.2251x over previous
//
#include <hip/hip_runtime.h>
#include <math.h>

#define N_NODES 50000
#define E_EDGES 800000
#define NEG_SLOPE 0.2f
#define BN_EPS 1e-5f
#define SCAN_NBLK ((N_NODES + 1023) / 1024)  // 49

// ---------------- init ----------------
__global__ void k_zero(int* __restrict__ counts, float* __restrict__ bn_sum,
                       float* __restrict__ bn_sumsq) {
  int i = blockIdx.x * 256 + threadIdx.x;
  if (i < N_NODES + 1) counts[i] = 0;
  if (i < 128) { bn_sum[i] = 0.f; bn_sumsq[i] = 0.f; }
}

// ---------------- CSR build ----------------
__global__ void k_hist(const int* __restrict__ dst, int* __restrict__ counts) {
  int e = blockIdx.x * 256 + threadIdx.x;
  if (e < E_EDGES) atomicAdd(&counts[dst[e]], 1);
}

// hierarchical exclusive scan: 49 blocks x 256 threads x 4 elements
__global__ __launch_bounds__(256) void k_scan1(const int* __restrict__ counts,
                                               int* __restrict__ tmp_scan,
                                               int* __restrict__ blk_sums) {
  __shared__ int ts[256];
  int t = threadIdx.x;
  int base = blockIdx.x * 1024 + t * 4;
  int c0 = (base + 0 < N_NODES) ? counts[base + 0] : 0;
  int c1 = (base + 1 < N_NODES) ? counts[base + 1] : 0;
  int c2 = (base + 2 < N_NODES) ? counts[base + 2] : 0;
  int c3 = (base + 3 < N_NODES) ? counts[base + 3] : 0;
  int s = c0 + c1 + c2 + c3;
  ts[t] = s;
  __syncthreads();
  for (int off = 1; off < 256; off <<= 1) {
    int v = (t >= off) ? ts[t - off] : 0;
    __syncthreads();
    ts[t] += v;
    __syncthreads();
  }
  int excl = ts[t] - s;
  if (t == 255) blk_sums[blockIdx.x] = ts[255];
  if (base + 0 < N_NODES) tmp_scan[base + 0] = excl;
  if (base + 1 < N_NODES) tmp_scan[base + 1] = excl + c0;
  if (base + 2 < N_NODES) tmp_scan[base + 2] = excl + c0 + c1;
  if (base + 3 < N_NODES) tmp_scan[base + 3] = excl + c0 + c1 + c2;
}

__global__ void k_scan2(int* __restrict__ blk_sums) {
  int t = threadIdx.x;  // single 64-lane wave
  int orig = (t < SCAN_NBLK) ? blk_sums[t] : 0;
  int v = orig;
#pragma unroll
  for (int off = 1; off < 64; off <<= 1) {
    int u = __shfl_up(v, off);
    if (t >= off) v += u;
  }
  if (t < SCAN_NBLK) blk_sums[t] = v - orig;  // exclusive
}

__global__ __launch_bounds__(256) void k_scan3(const int* __restrict__ tmp_scan,
                                               const int* __restrict__ blk_sums,
                                               int* __restrict__ row_ptr,
                                               int* __restrict__ cursor) {
  int i = blockIdx.x * 256 + threadIdx.x;
  if (i < N_NODES) {
    int v = tmp_scan[i] + blk_sums[i >> 10];
    row_ptr[i] = v;
    cursor[i] = v;
  }
  if (i == 0) row_ptr[N_NODES] = E_EDGES;  // counts always sum to E
}

__global__ void k_scatter(const int* __restrict__ src, const int* __restrict__ dst,
                          int* __restrict__ cursor, int* __restrict__ csr_src) {
  int e = blockIdx.x * 256 + threadIdx.x;
  if (e < E_EDGES) {
    int d = dst[e];
    int pos = atomicAdd(&cursor[d], 1);
    csr_src[pos] = src[e];
  }
}

// ---------------- layer 0 GEMM: h0 = x @ W0, + fused attention dots ----------------
// block 256 threads, tile 64 rows x 128 cols; thread: tr=t>>5 (8 rows each), tc=t&31 (4 cols each)
__global__ __launch_bounds__(256) void k_gemm0(
    const float* __restrict__ x, const float* __restrict__ W,
    const float* __restrict__ att_s, const float* __restrict__ att_d,
    float* __restrict__ h, float* __restrict__ a_src, float* __restrict__ a_dst) {
  __shared__ float xs[64 * 132];
  int t = threadIdx.x;
  int rowBase = blockIdx.x * 64;
#pragma unroll
  for (int j = 0; j < 8; j++) {
    int id = t + 256 * j;
    int row = id >> 5;
    int kk = (id & 31) * 4;
    float4 v = make_float4(0.f, 0.f, 0.f, 0.f);
    int gr = rowBase + row;
    if (gr < N_NODES) v = *(const float4*)&x[(size_t)gr * 128 + kk];
    *(float4*)&xs[row * 132 + kk] = v;
  }
  __syncthreads();

  int tc = t & 31, tr = t >> 5;
  int c = tc * 4, r0 = tr * 8;
  float acc[8][4];
#pragma unroll
  for (int i = 0; i < 8; i++)
#pragma unroll
    for (int j = 0; j < 4; j++) acc[i][j] = 0.f;

  for (int k4 = 0; k4 < 128; k4 += 4) {
    float4 wv[4];
#pragma unroll
    for (int kk = 0; kk < 4; kk++) wv[kk] = *(const float4*)&W[(k4 + kk) * 128 + c];
    float4 xv[8];
#pragma unroll
    for (int i = 0; i < 8; i++) xv[i] = *(const float4*)&xs[(r0 + i) * 132 + k4];
#pragma unroll
    for (int i = 0; i < 8; i++) {
      acc[i][0] += xv[i].x * wv[0].x + xv[i].y * wv[1].x + xv[i].z * wv[2].x + xv[i].w * wv[3].x;
      acc[i][1] += xv[i].x * wv[0].y + xv[i].y * wv[1].y + xv[i].z * wv[2].y + xv[i].w * wv[3].y;
      acc[i][2] += xv[i].x * wv[0].z + xv[i].y * wv[1].z + xv[i].z * wv[2].z + xv[i].w * wv[3].z;
      acc[i][3] += xv[i].x * wv[0].w + xv[i].y * wv[1].w + xv[i].z * wv[2].w + xv[i].w * wv[3].w;
    }
  }

  float as4[4], ad4[4];
#pragma unroll
  for (int j = 0; j < 4; j++) { as4[j] = att_s[c + j]; ad4[j] = att_d[c + j]; }
  int head = tc >> 4;
#pragma unroll
  for (int i = 0; i < 8; i++) {
    int gr = rowBase + r0 + i;
    float ps = acc[i][0] * as4[0] + acc[i][1] * as4[1] + acc[i][2] * as4[2] + acc[i][3] * as4[3];
    float pd = acc[i][0] * ad4[0] + acc[i][1] * ad4[1] + acc[i][2] * ad4[2] + acc[i][3] * ad4[3];
#pragma unroll
    for (int msk = 1; msk <= 8; msk <<= 1) {
      ps += __shfl_xor(ps, msk);
      pd += __shfl_xor(pd, msk);
    }
    if (gr < N_NODES) {
      float4 hv = make_float4(acc[i][0], acc[i][1], acc[i][2], acc[i][3]);
      *(float4*)&h[(size_t)gr * 128 + c] = hv;
      if ((t & 15) == 0) {
        a_src[gr * 2 + head] = ps;
        a_dst[gr * 2 + head] = pd;
      }
    }
  }
}

// ---------------- layer 0 aggregation: one wave per node, online softmax ----------------
__global__ __launch_bounds__(256) void k_agg0(
    const int* __restrict__ row_ptr, const int* __restrict__ csr_src,
    const float* __restrict__ h, const float* __restrict__ a_src,
    const float* __restrict__ a_dst, const float* __restrict__ bias,
    float* __restrict__ out) {
  int node = (blockIdx.x * blockDim.x + threadIdx.x) >> 6;
  if (node >= N_NODES) return;
  int l = threadIdx.x & 63;
  int head = l >> 5;
  int c = l * 2;
  float ad = a_dst[node * 2 + head];
  float e = a_src[node * 2 + head] + ad;
  e = e > 0.f ? e : NEG_SLOPE * e;  // self-loop edge
  float m = e, d = 1.f;
  float2 hv = *(const float2*)&h[(size_t)node * 128 + c];
  float acc0 = hv.x, acc1 = hv.y;
  int beg = row_ptr[node], end = row_ptr[node + 1];
  for (int i = beg; i < end; i++) {
    int s = csr_src[i];
    float ee = a_src[s * 2 + head] + ad;
    ee = ee > 0.f ? ee : NEG_SLOPE * ee;
    float2 hh = *(const float2*)&h[(size_t)s * 128 + c];
    float nm = fmaxf(m, ee);
    float sc = __expf(m - nm);
    float w = __expf(ee - nm);
    d = d * sc + w;
    acc0 = acc0 * sc + w * hh.x;
    acc1 = acc1 * sc + w * hh.y;
    m = nm;
  }
  float inv = 1.f / d;
  float2 o;
  o.x = acc0 * inv + bias[c];
  o.y = acc1 * inv + bias[c + 1];
  *(float2*)&out[(size_t)node * 128 + c] = o;
}

// ---------------- BatchNorm stats ----------------
__global__ __launch_bounds__(256) void k_bnstats(const float* __restrict__ x,
                                                 float* __restrict__ bn_sum,
                                                 float* __restrict__ bn_sumsq) {
  int f = threadIdx.x & 127;
  int half = threadIdx.x >> 7;
  float s = 0.f, s2 = 0.f;
  for (int r = blockIdx.x * 2 + half; r < N_NODES; r += gridDim.x * 2) {
    float v = x[(size_t)r * 128 + f];
    s += v;
    s2 += v * v;
  }
  __shared__ float ls[256], ls2[256];
  ls[threadIdx.x] = s;
  ls2[threadIdx.x] = s2;
  __syncthreads();
  if (half == 0) {
    atomicAdd(&bn_sum[f], s + ls[f + 128]);
    atomicAdd(&bn_sumsq[f], s2 + ls2[f + 128]);
  }
}

__global__ void k_bnfinal(const float* __restrict__ sum, const float* __restrict__ sumsq,
                          const float* __restrict__ gamma, const float* __restrict__ beta,
                          float* __restrict__ scale, float* __restrict__ shift) {
  int f = threadIdx.x;
  float mu = sum[f] / (float)N_NODES;
  float var = sumsq[f] / (float)N_NODES - mu * mu;
  float sc = gamma[f] * rsqrtf(var + BN_EPS);
  scale[f] = sc;
  shift[f] = beta[f] - mu * sc;
}

// ---------------- layer 1 GEMM (BN+ELU fused on load): h1 = elu(bn(out0)) @ W1 ----------------
__global__ __launch_bounds__(256) void k_gemm1(
    const float* __restrict__ x, const float* __restrict__ W,
    const float* __restrict__ scale, const float* __restrict__ shift,
    const float* __restrict__ att_s, const float* __restrict__ att_d,
    float* __restrict__ h, float* __restrict__ a_src, float* __restrict__ a_dst) {
  __shared__ float xs[64 * 132];
  int t = threadIdx.x;
  int rowBase = blockIdx.x * 64;
#pragma unroll
  for (int j = 0; j < 8; j++) {
    int id = t + 256 * j;
    int row = id >> 5;
    int kk = (id & 31) * 4;
    float4 v = make_float4(0.f, 0.f, 0.f, 0.f);
    int gr = rowBase + row;
    if (gr < N_NODES) {
      float4 raw = *(const float4*)&x[(size_t)gr * 128 + kk];
      float4 sc = *(const float4*)&scale[kk];
      float4 sh = *(const float4*)&shift[kk];
      v.x = raw.x * sc.x + sh.x;
      v.y = raw.y * sc.y + sh.y;
      v.z = raw.z * sc.z + sh.z;
      v.w = raw.w * sc.w + sh.w;
      v.x = v.x > 0.f ? v.x : __expf(v.x) - 1.f;
      v.y = v.y > 0.f ? v.y : __expf(v.y) - 1.f;
      v.z = v.z > 0.f ? v.z : __expf(v.z) - 1.f;
      v.w = v.w > 0.f ? v.w : __expf(v.w) - 1.f;
    }
    *(float4*)&xs[row * 132 + kk] = v;
  }
  __syncthreads();

  int tc = t & 15, tr = t >> 4;
  int c = tc * 4, r0 = tr * 4;
  float acc[4][4];
#pragma unroll
  for (int i = 0; i < 4; i++)
#pragma unroll
    for (int j = 0; j < 4; j++) acc[i][j] = 0.f;

  for (int k4 = 0; k4 < 128; k4 += 4) {
    float4 wv[4];
#pragma unroll
    for (int kk = 0; kk < 4; kk++) wv[kk] = *(const float4*)&W[(k4 + kk) * 64 + c];
    float4 xv[4];
#pragma unroll
    for (int i = 0; i < 4; i++) xv[i] = *(const float4*)&xs[(r0 + i) * 132 + k4];
#pragma unroll
    for (int i = 0; i < 4; i++) {
      acc[i][0] += xv[i].x * wv[0].x + xv[i].y * wv[1].x + xv[i].z * wv[2].x + xv[i].w * wv[3].x;
      acc[i][1] += xv[i].x * wv[0].y + xv[i].y * wv[1].y + xv[i].z * wv[2].y + xv[i].w * wv[3].y;
      acc[i][2] += xv[i].x * wv[0].z + xv[i].y * wv[1].z + xv[i].z * wv[2].z + xv[i].w * wv[3].z;
      acc[i][3] += xv[i].x * wv[0].w + xv[i].y * wv[1].w + xv[i].z * wv[2].w + xv[i].w * wv[3].w;
    }
  }

  float as4[4], ad4[4];
#pragma unroll
  for (int j = 0; j < 4; j++) { as4[j] = att_s[c + j]; ad4[j] = att_d[c + j]; }
#pragma unroll
  for (int i = 0; i < 4; i++) {
    int gr = rowBase + r0 + i;
    float ps = acc[i][0] * as4[0] + acc[i][1] * as4[1] + acc[i][2] * as4[2] + acc[i][3] * as4[3];
    float pd = acc[i][0] * ad4[0] + acc[i][1] * ad4[1] + acc[i][2] * ad4[2] + acc[i][3] * ad4[3];
#pragma unroll
    for (int msk = 1; msk <= 8; msk <<= 1) {
      ps += __shfl_xor(ps, msk);
      pd += __shfl_xor(pd, msk);
    }
    if (gr < N_NODES) {
      float4 hv = make_float4(acc[i][0], acc[i][1], acc[i][2], acc[i][3]);
      *(float4*)&h[(size_t)gr * 64 + c] = hv;
      if ((t & 15) == 0) {
        a_src[gr] = ps;
        a_dst[gr] = pd;
      }
    }
  }
}

// ---------------- layer 1 aggregation ----------------
__global__ __launch_bounds__(256) void k_agg1(
    const int* __restrict__ row_ptr, const int* __restrict__ csr_src,
    const float* __restrict__ h, const float* __restrict__ a_src,
    const float* __restrict__ a_dst, const float* __restrict__ bias,
    float* __restrict__ out) {
  int node = (blockIdx.x * blockDim.x + threadIdx.x) >> 6;
  if (node >= N_NODES) return;
  int l = threadIdx.x & 63;
  float ad = a_dst[node];
  float e = a_src[node] + ad;
  e = e > 0.f ? e : NEG_SLOPE * e;  // self loop
  float m = e, d = 1.f;
  float acc = h[(size_t)node * 64 + l];
  int beg = row_ptr[node], end = row_ptr[node + 1];
  for (int i = beg; i < end; i++) {
    int s = csr_src[i];
    float ee = a_src[s] + ad;
    ee = ee > 0.f ? ee : NEG_SLOPE * ee;
    float hh = h[(size_t)s * 64 + l];
    float nm = fmaxf(m, ee);
    float sc = __expf(m - nm);
    float w = __expf(ee - nm);
    d = d * sc + w;
    acc = acc * sc + w * hh;
    m = nm;
  }
  out[(size_t)node * 64 + l] = acc / d + bias[l];
}

// ---------------- launch ----------------
extern "C" void kernel_launch(void* const* d_in, const int* in_sizes, int n_in,
                              void* d_out, int out_size, void* d_ws, size_t ws_size,
                              hipStream_t stream) {
  const float* data = (const float*)d_in[0];
  const int* ei = (const int*)d_in[1];
  const float* W0 = (const float*)d_in[2];
  const float* att_src0 = (const float*)d_in[3];
  const float* att_dst0 = (const float*)d_in[4];
  const float* bias0 = (const float*)d_in[5];
  const float* gamma0 = (const float*)d_in[6];
  const float* beta0 = (const float*)d_in[7];
  const float* W1 = (const float*)d_in[8];
  const float* att_src1 = (const float*)d_in[9];
  const float* att_dst1 = (const float*)d_in[10];
  const float* bias1 = (const float*)d_in[11];
  float* out = (float*)d_out;

  char* ws = (char*)d_ws;
  size_t off = 0;
  auto alloc = [&](size_t bytes) -> void* {
    void* p = ws + off;
    off = (off + bytes + 255) & ~(size_t)255;
    return p;
  };
  int* row_ptr = (int*)alloc((N_NODES + 1) * 4);
  int* counts = (int*)alloc((N_NODES + 1) * 4);
  int* cursor = (int*)alloc(N_NODES * 4);
  int* tmp_scan = (int*)alloc((size_t)N_NODES * 4);
  int* blk_sums = (int*)alloc(64 * 4);
  int* csr_src = (int*)alloc((size_t)E_EDGES * 4);
  float* h0 = (float*)alloc((size_t)N_NODES * 128 * 4);
  float* a_s0 = (float*)alloc((size_t)N_NODES * 2 * 4);
  float* a_d0 = (float*)alloc((size_t)N_NODES * 2 * 4);
  float* out0 = (float*)alloc((size_t)N_NODES * 128 * 4);
  float* bn_sum = (float*)alloc(128 * 4);
  float* bn_sumsq = (float*)alloc(128 * 4);
  float* bn_scale = (float*)alloc(128 * 4);
  float* bn_shift = (float*)alloc(128 * 4);
  float* h1 = h0;    // layer-1 buffers alias dead layer-0 buffers
  float* a_s1 = a_s0;
  float* a_d1 = a_d0;

  const int* srcArr = ei;
  const int* dstArr = ei + E_EDGES;

  k_zero<<<(N_NODES + 256) / 256, 256, 0, stream>>>(counts, bn_sum, bn_sumsq);
  k_hist<<<(E_EDGES + 255) / 256, 256, 0, stream>>>(dstArr, counts);
  k_scan1<<<SCAN_NBLK, 256, 0, stream>>>(counts, tmp_scan, blk_sums);
  k_scan2<<<1, 64, 0, stream>>>(blk_sums);
  k_scan3<<<(N_NODES + 255) / 256, 256, 0, stream>>>(tmp_scan, blk_sums, row_ptr, cursor);
  k_scatter<<<(E_EDGES + 255) / 256, 256, 0, stream>>>(srcArr, dstArr, cursor, csr_src);
  k_gemm0<<<(N_NODES + 63) / 64, 256, 0, stream>>>(data, W0, att_src0, att_dst0, h0, a_s0, a_d0);
  k_agg0<<<(N_NODES + 3) / 4, 256, 0, stream>>>(row_ptr, csr_src, h0, a_s0, a_d0, bias0, out0);
  k_bnstats<<<1024, 256, 0, stream>>>(out0, bn_sum, bn_sumsq);
  k_bnfinal<<<1, 128, 0, stream>>>(bn_sum, bn_sumsq, gamma0, beta0, bn_scale, bn_shift);
  k_gemm1<<<(N_NODES + 63) / 64, 256, 0, stream>>>(out0, W1, bn_scale, bn_shift, att_src1,
                                                   att_dst1, h1, a_s1, a_d1);
  k_agg1<<<(N_NODES + 3) / 4, 256, 0, stream>>>(row_ptr, csr_src, h1, a_s1, a_d1, bias1, out);
}

// Round 4
// 352.974 us; speedup vs baseline: 1.5832x; 1.2923x over previous
//
#include <hip/hip_runtime.h>
#include <hip/hip_fp16.h>
#include <math.h>

#define N_NODES 50000
#define E_EDGES 800000
#define NEG_SLOPE 0.2f
#define BN_EPS 1e-5f
#define SCAN_NBLK ((N_NODES + 1023) / 1024)  // 49

__device__ __forceinline__ float lrelu(float v) { return v > 0.f ? v : NEG_SLOPE * v; }

// ---------------- init ----------------
__global__ void k_zero(int* __restrict__ counts, float* __restrict__ bn_sum,
                       float* __restrict__ bn_sumsq) {
  int i = blockIdx.x * 256 + threadIdx.x;
  if (i < N_NODES + 1) counts[i] = 0;
  if (i < 128) { bn_sum[i] = 0.f; bn_sumsq[i] = 0.f; }
}

// ---------------- CSR build ----------------
__global__ void k_hist(const int* __restrict__ dst, int* __restrict__ counts) {
  int e = blockIdx.x * 256 + threadIdx.x;
  if (e < E_EDGES) atomicAdd(&counts[dst[e]], 1);
}

// hierarchical exclusive scan: 49 blocks x 256 threads x 4 elements
__global__ __launch_bounds__(256) void k_scan1(const int* __restrict__ counts,
                                               int* __restrict__ tmp_scan,
                                               int* __restrict__ blk_sums) {
  __shared__ int ts[256];
  int t = threadIdx.x;
  int base = blockIdx.x * 1024 + t * 4;
  int c0 = (base + 0 < N_NODES) ? counts[base + 0] : 0;
  int c1 = (base + 1 < N_NODES) ? counts[base + 1] : 0;
  int c2 = (base + 2 < N_NODES) ? counts[base + 2] : 0;
  int c3 = (base + 3 < N_NODES) ? counts[base + 3] : 0;
  int s = c0 + c1 + c2 + c3;
  ts[t] = s;
  __syncthreads();
  for (int off = 1; off < 256; off <<= 1) {
    int v = (t >= off) ? ts[t - off] : 0;
    __syncthreads();
    ts[t] += v;
    __syncthreads();
  }
  int excl = ts[t] - s;
  if (t == 255) blk_sums[blockIdx.x] = ts[255];
  if (base + 0 < N_NODES) tmp_scan[base + 0] = excl;
  if (base + 1 < N_NODES) tmp_scan[base + 1] = excl + c0;
  if (base + 2 < N_NODES) tmp_scan[base + 2] = excl + c0 + c1;
  if (base + 3 < N_NODES) tmp_scan[base + 3] = excl + c0 + c1 + c2;
}

__global__ void k_scan2(int* __restrict__ blk_sums) {
  int t = threadIdx.x;  // single 64-lane wave
  int orig = (t < SCAN_NBLK) ? blk_sums[t] : 0;
  int v = orig;
#pragma unroll
  for (int off = 1; off < 64; off <<= 1) {
    int u = __shfl_up(v, off);
    if (t >= off) v += u;
  }
  if (t < SCAN_NBLK) blk_sums[t] = v - orig;  // exclusive
}

__global__ __launch_bounds__(256) void k_scan3(const int* __restrict__ tmp_scan,
                                               const int* __restrict__ blk_sums,
                                               int* __restrict__ row_ptr,
                                               int* __restrict__ cursor) {
  int i = blockIdx.x * 256 + threadIdx.x;
  if (i < N_NODES) {
    int v = tmp_scan[i] + blk_sums[i >> 10];
    row_ptr[i] = v;
    cursor[i] = v;
  }
  if (i == 0) row_ptr[N_NODES] = E_EDGES;  // counts always sum to E
}

__global__ void k_scatter(const int* __restrict__ src, const int* __restrict__ dst,
                          int* __restrict__ cursor, int* __restrict__ csr_src) {
  int e = blockIdx.x * 256 + threadIdx.x;
  if (e < E_EDGES) {
    int d = dst[e];
    int pos = atomicAdd(&cursor[d], 1);
    csr_src[pos] = src[e];
  }
}

// ---------------- layer 0 GEMM: h0 = x @ W0 (fp16 out), + fused attention dots ----------------
__global__ __launch_bounds__(256) void k_gemm0(
    const float* __restrict__ x, const float* __restrict__ W,
    const float* __restrict__ att_s, const float* __restrict__ att_d,
    __half* __restrict__ h, float* __restrict__ a_src, float* __restrict__ a_dst) {
  __shared__ float xs[64 * 132];
  int t = threadIdx.x;
  int rowBase = blockIdx.x * 64;
#pragma unroll
  for (int j = 0; j < 8; j++) {
    int id = t + 256 * j;
    int row = id >> 5;
    int kk = (id & 31) * 4;
    float4 v = make_float4(0.f, 0.f, 0.f, 0.f);
    int gr = rowBase + row;
    if (gr < N_NODES) v = *(const float4*)&x[(size_t)gr * 128 + kk];
    *(float4*)&xs[row * 132 + kk] = v;
  }
  __syncthreads();

  int tc = t & 31, tr = t >> 5;
  int c = tc * 4, r0 = tr * 8;
  float acc[8][4];
#pragma unroll
  for (int i = 0; i < 8; i++)
#pragma unroll
    for (int j = 0; j < 4; j++) acc[i][j] = 0.f;

  for (int k4 = 0; k4 < 128; k4 += 4) {
    float4 wv[4];
#pragma unroll
    for (int kk = 0; kk < 4; kk++) wv[kk] = *(const float4*)&W[(k4 + kk) * 128 + c];
    float4 xv[8];
#pragma unroll
    for (int i = 0; i < 8; i++) xv[i] = *(const float4*)&xs[(r0 + i) * 132 + k4];
#pragma unroll
    for (int i = 0; i < 8; i++) {
      acc[i][0] += xv[i].x * wv[0].x + xv[i].y * wv[1].x + xv[i].z * wv[2].x + xv[i].w * wv[3].x;
      acc[i][1] += xv[i].x * wv[0].y + xv[i].y * wv[1].y + xv[i].z * wv[2].y + xv[i].w * wv[3].y;
      acc[i][2] += xv[i].x * wv[0].z + xv[i].y * wv[1].z + xv[i].z * wv[2].z + xv[i].w * wv[3].z;
      acc[i][3] += xv[i].x * wv[0].w + xv[i].y * wv[1].w + xv[i].z * wv[2].w + xv[i].w * wv[3].w;
    }
  }

  float as4[4], ad4[4];
#pragma unroll
  for (int j = 0; j < 4; j++) { as4[j] = att_s[c + j]; ad4[j] = att_d[c + j]; }
  int head = tc >> 4;
#pragma unroll
  for (int i = 0; i < 8; i++) {
    int gr = rowBase + r0 + i;
    float ps = acc[i][0] * as4[0] + acc[i][1] * as4[1] + acc[i][2] * as4[2] + acc[i][3] * as4[3];
    float pd = acc[i][0] * ad4[0] + acc[i][1] * ad4[1] + acc[i][2] * ad4[2] + acc[i][3] * ad4[3];
#pragma unroll
    for (int msk = 1; msk <= 8; msk <<= 1) {
      ps += __shfl_xor(ps, msk);
      pd += __shfl_xor(pd, msk);
    }
    if (gr < N_NODES) {
      __half2 p01 = __floats2half2_rn(acc[i][0], acc[i][1]);
      __half2 p23 = __floats2half2_rn(acc[i][2], acc[i][3]);
      uint2 pk;
      pk.x = *(unsigned int*)&p01;
      pk.y = *(unsigned int*)&p23;
      *(uint2*)&h[(size_t)gr * 128 + c] = pk;
      if ((t & 15) == 0) {
        a_src[gr * 2 + head] = ps;
        a_dst[gr * 2 + head] = pd;
      }
    }
  }
}

// ---------------- layer 0 aggregation: wave per node, batched-4 online softmax, fp16 h ----------
__global__ __launch_bounds__(256) void k_agg0(
    const int* __restrict__ row_ptr, const int* __restrict__ csr_src,
    const __half* __restrict__ h, const float* __restrict__ a_src,
    const float* __restrict__ a_dst, const float* __restrict__ bias,
    float* __restrict__ out) {
  int node = (blockIdx.x * blockDim.x + threadIdx.x) >> 6;
  if (node >= N_NODES) return;
  int l = threadIdx.x & 63;
  int head = l >> 5;
  int c = l * 2;
  float ad = a_dst[node * 2 + head];
  float m = lrelu(a_src[node * 2 + head] + ad);  // self-loop
  float d = 1.f;
  __half2 hvp = *(const __half2*)&h[(size_t)node * 128 + c];
  float2 hv = __half22float2(hvp);
  float acc0 = hv.x, acc1 = hv.y;
  int beg = row_ptr[node], end = row_ptr[node + 1];
  int i = beg;
  for (; i + 4 <= end; i += 4) {
    int s0 = csr_src[i], s1 = csr_src[i + 1], s2 = csr_src[i + 2], s3 = csr_src[i + 3];
    float e0 = lrelu(a_src[s0 * 2 + head] + ad);
    float e1 = lrelu(a_src[s1 * 2 + head] + ad);
    float e2 = lrelu(a_src[s2 * 2 + head] + ad);
    float e3 = lrelu(a_src[s3 * 2 + head] + ad);
    __half2 p0 = *(const __half2*)&h[(size_t)s0 * 128 + c];
    __half2 p1 = *(const __half2*)&h[(size_t)s1 * 128 + c];
    __half2 p2 = *(const __half2*)&h[(size_t)s2 * 128 + c];
    __half2 p3 = *(const __half2*)&h[(size_t)s3 * 128 + c];
    float nm = fmaxf(fmaxf(m, e0), fmaxf(fmaxf(e1, e2), e3));
    float sc = __expf(m - nm);
    float w0 = __expf(e0 - nm), w1 = __expf(e1 - nm);
    float w2 = __expf(e2 - nm), w3 = __expf(e3 - nm);
    d = d * sc + (w0 + w1) + (w2 + w3);
    float2 f0 = __half22float2(p0), f1 = __half22float2(p1);
    float2 f2 = __half22float2(p2), f3 = __half22float2(p3);
    acc0 = acc0 * sc + w0 * f0.x + w1 * f1.x + w2 * f2.x + w3 * f3.x;
    acc1 = acc1 * sc + w0 * f0.y + w1 * f1.y + w2 * f2.y + w3 * f3.y;
    m = nm;
  }
  for (; i < end; i++) {
    int s = csr_src[i];
    float ee = lrelu(a_src[s * 2 + head] + ad);
    __half2 pp = *(const __half2*)&h[(size_t)s * 128 + c];
    float nm = fmaxf(m, ee);
    float sc = __expf(m - nm);
    float w = __expf(ee - nm);
    float2 ff = __half22float2(pp);
    d = d * sc + w;
    acc0 = acc0 * sc + w * ff.x;
    acc1 = acc1 * sc + w * ff.y;
    m = nm;
  }
  float inv = 1.f / d;
  float2 o;
  o.x = acc0 * inv + bias[c];
  o.y = acc1 * inv + bias[c + 1];
  *(float2*)&out[(size_t)node * 128 + c] = o;
}

// ---------------- BatchNorm stats ----------------
__global__ __launch_bounds__(256) void k_bnstats(const float* __restrict__ x,
                                                 float* __restrict__ bn_sum,
                                                 float* __restrict__ bn_sumsq) {
  int f = threadIdx.x & 127;
  int half = threadIdx.x >> 7;
  float s = 0.f, s2 = 0.f;
  for (int r = blockIdx.x * 2 + half; r < N_NODES; r += gridDim.x * 2) {
    float v = x[(size_t)r * 128 + f];
    s += v;
    s2 += v * v;
  }
  __shared__ float ls[256], ls2[256];
  ls[threadIdx.x] = s;
  ls2[threadIdx.x] = s2;
  __syncthreads();
  if (half == 0) {
    atomicAdd(&bn_sum[f], s + ls[f + 128]);
    atomicAdd(&bn_sumsq[f], s2 + ls2[f + 128]);
  }
}

__global__ void k_bnfinal(const float* __restrict__ sum, const float* __restrict__ sumsq,
                          const float* __restrict__ gamma, const float* __restrict__ beta,
                          float* __restrict__ scale, float* __restrict__ shift) {
  int f = threadIdx.x;
  float mu = sum[f] / (float)N_NODES;
  float var = sumsq[f] / (float)N_NODES - mu * mu;
  float sc = gamma[f] * rsqrtf(var + BN_EPS);
  scale[f] = sc;
  shift[f] = beta[f] - mu * sc;
}

// ---------------- layer 1 GEMM (BN+ELU fused on load), fp16 h out ----------------
__global__ __launch_bounds__(256) void k_gemm1(
    const float* __restrict__ x, const float* __restrict__ W,
    const float* __restrict__ scale, const float* __restrict__ shift,
    const float* __restrict__ att_s, const float* __restrict__ att_d,
    __half* __restrict__ h, float* __restrict__ a_src, float* __restrict__ a_dst) {
  __shared__ float xs[64 * 132];
  int t = threadIdx.x;
  int rowBase = blockIdx.x * 64;
#pragma unroll
  for (int j = 0; j < 8; j++) {
    int id = t + 256 * j;
    int row = id >> 5;
    int kk = (id & 31) * 4;
    float4 v = make_float4(0.f, 0.f, 0.f, 0.f);
    int gr = rowBase + row;
    if (gr < N_NODES) {
      float4 raw = *(const float4*)&x[(size_t)gr * 128 + kk];
      float4 sc = *(const float4*)&scale[kk];
      float4 sh = *(const float4*)&shift[kk];
      v.x = raw.x * sc.x + sh.x;
      v.y = raw.y * sc.y + sh.y;
      v.z = raw.z * sc.z + sh.z;
      v.w = raw.w * sc.w + sh.w;
      v.x = v.x > 0.f ? v.x : __expf(v.x) - 1.f;
      v.y = v.y > 0.f ? v.y : __expf(v.y) - 1.f;
      v.z = v.z > 0.f ? v.z : __expf(v.z) - 1.f;
      v.w = v.w > 0.f ? v.w : __expf(v.w) - 1.f;
    }
    *(float4*)&xs[row * 132 + kk] = v;
  }
  __syncthreads();

  int tc = t & 15, tr = t >> 4;
  int c = tc * 4, r0 = tr * 4;
  float acc[4][4];
#pragma unroll
  for (int i = 0; i < 4; i++)
#pragma unroll
    for (int j = 0; j < 4; j++) acc[i][j] = 0.f;

  for (int k4 = 0; k4 < 128; k4 += 4) {
    float4 wv[4];
#pragma unroll
    for (int kk = 0; kk < 4; kk++) wv[kk] = *(const float4*)&W[(k4 + kk) * 64 + c];
    float4 xv[4];
#pragma unroll
    for (int i = 0; i < 4; i++) xv[i] = *(const float4*)&xs[(r0 + i) * 132 + k4];
#pragma unroll
    for (int i = 0; i < 4; i++) {
      acc[i][0] += xv[i].x * wv[0].x + xv[i].y * wv[1].x + xv[i].z * wv[2].x + xv[i].w * wv[3].x;
      acc[i][1] += xv[i].x * wv[0].y + xv[i].y * wv[1].y + xv[i].z * wv[2].y + xv[i].w * wv[3].y;
      acc[i][2] += xv[i].x * wv[0].z + xv[i].y * wv[1].z + xv[i].z * wv[2].z + xv[i].w * wv[3].z;
      acc[i][3] += xv[i].x * wv[0].w + xv[i].y * wv[1].w + xv[i].z * wv[2].w + xv[i].w * wv[3].w;
    }
  }

  float as4[4], ad4[4];
#pragma unroll
  for (int j = 0; j < 4; j++) { as4[j] = att_s[c + j]; ad4[j] = att_d[c + j]; }
#pragma unroll
  for (int i = 0; i < 4; i++) {
    int gr = rowBase + r0 + i;
    float ps = acc[i][0] * as4[0] + acc[i][1] * as4[1] + acc[i][2] * as4[2] + acc[i][3] * as4[3];
    float pd = acc[i][0] * ad4[0] + acc[i][1] * ad4[1] + acc[i][2] * ad4[2] + acc[i][3] * ad4[3];
#pragma unroll
    for (int msk = 1; msk <= 8; msk <<= 1) {
      ps += __shfl_xor(ps, msk);
      pd += __shfl_xor(pd, msk);
    }
    if (gr < N_NODES) {
      __half2 p01 = __floats2half2_rn(acc[i][0], acc[i][1]);
      __half2 p23 = __floats2half2_rn(acc[i][2], acc[i][3]);
      uint2 pk;
      pk.x = *(unsigned int*)&p01;
      pk.y = *(unsigned int*)&p23;
      *(uint2*)&h[(size_t)gr * 64 + c] = pk;
      if ((t & 15) == 0) {
        a_src[gr] = ps;
        a_dst[gr] = pd;
      }
    }
  }
}

// ---------------- layer 1 aggregation: batched-4, fp16 h ----------------
__global__ __launch_bounds__(256) void k_agg1(
    const int* __restrict__ row_ptr, const int* __restrict__ csr_src,
    const __half* __restrict__ h, const float* __restrict__ a_src,
    const float* __restrict__ a_dst, const float* __restrict__ bias,
    float* __restrict__ out) {
  int node = (blockIdx.x * blockDim.x + threadIdx.x) >> 6;
  if (node >= N_NODES) return;
  int l = threadIdx.x & 63;
  float ad = a_dst[node];
  float m = lrelu(a_src[node] + ad);  // self loop
  float d = 1.f;
  float acc = __half2float(h[(size_t)node * 64 + l]);
  int beg = row_ptr[node], end = row_ptr[node + 1];
  int i = beg;
  for (; i + 4 <= end; i += 4) {
    int s0 = csr_src[i], s1 = csr_src[i + 1], s2 = csr_src[i + 2], s3 = csr_src[i + 3];
    float e0 = lrelu(a_src[s0] + ad);
    float e1 = lrelu(a_src[s1] + ad);
    float e2 = lrelu(a_src[s2] + ad);
    float e3 = lrelu(a_src[s3] + ad);
    __half p0 = h[(size_t)s0 * 64 + l];
    __half p1 = h[(size_t)s1 * 64 + l];
    __half p2 = h[(size_t)s2 * 64 + l];
    __half p3 = h[(size_t)s3 * 64 + l];
    float nm = fmaxf(fmaxf(m, e0), fmaxf(fmaxf(e1, e2), e3));
    float sc = __expf(m - nm);
    float w0 = __expf(e0 - nm), w1 = __expf(e1 - nm);
    float w2 = __expf(e2 - nm), w3 = __expf(e3 - nm);
    d = d * sc + (w0 + w1) + (w2 + w3);
    acc = acc * sc + w0 * __half2float(p0) + w1 * __half2float(p1) +
          w2 * __half2float(p2) + w3 * __half2float(p3);
    m = nm;
  }
  for (; i < end; i++) {
    int s = csr_src[i];
    float ee = lrelu(a_src[s] + ad);
    __half pp = h[(size_t)s * 64 + l];
    float nm = fmaxf(m, ee);
    float sc = __expf(m - nm);
    float w = __expf(ee - nm);
    d = d * sc + w;
    acc = acc * sc + w * __half2float(pp);
    m = nm;
  }
  out[(size_t)node * 64 + l] = acc / d + bias[l];
}

// ---------------- launch ----------------
extern "C" void kernel_launch(void* const* d_in, const int* in_sizes, int n_in,
                              void* d_out, int out_size, void* d_ws, size_t ws_size,
                              hipStream_t stream) {
  const float* data = (const float*)d_in[0];
  const int* ei = (const int*)d_in[1];
  const float* W0 = (const float*)d_in[2];
  const float* att_src0 = (const float*)d_in[3];
  const float* att_dst0 = (const float*)d_in[4];
  const float* bias0 = (const float*)d_in[5];
  const float* gamma0 = (const float*)d_in[6];
  const float* beta0 = (const float*)d_in[7];
  const float* W1 = (const float*)d_in[8];
  const float* att_src1 = (const float*)d_in[9];
  const float* att_dst1 = (const float*)d_in[10];
  const float* bias1 = (const float*)d_in[11];
  float* out = (float*)d_out;

  char* ws = (char*)d_ws;
  size_t off = 0;
  auto alloc = [&](size_t bytes) -> void* {
    void* p = ws + off;
    off = (off + bytes + 255) & ~(size_t)255;
    return p;
  };
  int* row_ptr = (int*)alloc((N_NODES + 1) * 4);
  int* counts = (int*)alloc((N_NODES + 1) * 4);
  int* cursor = (int*)alloc(N_NODES * 4);
  int* tmp_scan = (int*)alloc((size_t)N_NODES * 4);
  int* blk_sums = (int*)alloc(64 * 4);
  int* csr_src = (int*)alloc((size_t)E_EDGES * 4);
  __half* h0 = (__half*)alloc((size_t)N_NODES * 128 * 2);  // fp16 h
  float* a_s0 = (float*)alloc((size_t)N_NODES * 2 * 4);
  float* a_d0 = (float*)alloc((size_t)N_NODES * 2 * 4);
  float* out0 = (float*)alloc((size_t)N_NODES * 128 * 4);
  float* bn_sum = (float*)alloc(128 * 4);
  float* bn_sumsq = (float*)alloc(128 * 4);
  float* bn_scale = (float*)alloc(128 * 4);
  float* bn_shift = (float*)alloc(128 * 4);
  __half* h1 = h0;   // layer-1 buffers alias dead layer-0 buffers
  float* a_s1 = a_s0;
  float* a_d1 = a_d0;

  const int* srcArr = ei;
  const int* dstArr = ei + E_EDGES;

  k_zero<<<(N_NODES + 256) / 256, 256, 0, stream>>>(counts, bn_sum, bn_sumsq);
  k_hist<<<(E_EDGES + 255) / 256, 256, 0, stream>>>(dstArr, counts);
  k_scan1<<<SCAN_NBLK, 256, 0, stream>>>(counts, tmp_scan, blk_sums);
  k_scan2<<<1, 64, 0, stream>>>(blk_sums);
  k_scan3<<<(N_NODES + 255) / 256, 256, 0, stream>>>(tmp_scan, blk_sums, row_ptr, cursor);
  k_scatter<<<(E_EDGES + 255) / 256, 256, 0, stream>>>(srcArr, dstArr, cursor, csr_src);
  k_gemm0<<<(N_NODES + 63) / 64, 256, 0, stream>>>(data, W0, att_src0, att_dst0, h0, a_s0, a_d0);
  k_agg0<<<(N_NODES + 3) / 4, 256, 0, stream>>>(row_ptr, csr_src, h0, a_s0, a_d0, bias0, out0);
  k_bnstats<<<1024, 256, 0, stream>>>(out0, bn_sum, bn_sumsq);
  k_bnfinal<<<1, 128, 0, stream>>>(bn_sum, bn_sumsq, gamma0, beta0, bn_scale, bn_shift);
  k_gemm1<<<(N_NODES + 63) / 64, 256, 0, stream>>>(out0, W1, bn_scale, bn_shift, att_src1,
                                                   att_dst1, h1, a_s1, a_d1);
  k_agg1<<<(N_NODES + 3) / 4, 256, 0, stream>>>(row_ptr, csr_src, h1, a_s1, a_d1, bias1, out);
}